// Round 8
// baseline (453.963 us; speedup 1.0000x reference)
//
#include <hip/hip_runtime.h>
#include <stdint.h>

// Problem constants (fixed by the reference):
#define NB 4
#define NN 50000
#define NE 800000
#define NF 128

#define NNP   50176          // 49*1024, padded counter stride
#define NCPY  8              // counter privatization factor (copy = e & 7)
#define NTILE 1563           // ceil(NB*NN / 128) GEMM row tiles
#define LDW   136            // W-LDS / epilogue-tile row stride in bf16 (128 + 8 pad)

typedef __attribute__((ext_vector_type(8))) short  bfrag;    // 8 bf16 (4 VGPR)
typedef __attribute__((ext_vector_type(4))) float  ffrag;    // 4 fp32 acc
typedef __attribute__((ext_vector_type(4))) short  short4v;  // 8 B LDS store

// fp32 -> bf16 round-to-nearest-even
__device__ inline unsigned short f2bf(float f) {
    unsigned int u = __builtin_bit_cast(unsigned int, f);
    u += 0x7fffu + ((u >> 16) & 1u);
    return (unsigned short)(u >> 16);
}
__device__ inline float bflo(unsigned int u) { return __builtin_bit_cast(float, u << 16); }
__device__ inline float bfhi(unsigned int u) { return __builtin_bit_cast(float, u & 0xffff0000u); }

// ---------------------------------------------------------------------------
// GEMM (+fused 8-way privatized histogram): h[n][b][o] = bf16(x @ W^T).
// W staged to LDS once per block behind one barrier; x streamed straight from
// global into MFMA fragments (no barriers in the K-loop).  UNCHANGED from R7
// for clean attribution.
// ---------------------------------------------------------------------------
__global__ __launch_bounds__(256) void gemm_kernel(
    const float* __restrict__ x,        // [M][NF] fp32
    const float* __restrict__ W,        // [NF][NF] fp32 (row = out feature)
    unsigned short* __restrict__ h,     // [NN][NB][NF] bf16, node-major
    const int* __restrict__ erow,
    int* __restrict__ cnt8,             // [NCPY][NNP] privatized histogram (zeroed)
    int M)
{
    __shared__ short wsh[128 * LDW];    // 34.8 KB: W bf16, then epilogue tile

    const int tid = threadIdx.x;

    // --- fused histogram (overlaps with W staging + first x loads) ---
    for (int e = blockIdx.x * 256 + tid; e < NE; e += gridDim.x * 256)
        atomicAdd(&cnt8[(e & 7) * NNP + erow[e]], 1);

    // --- stage W -> LDS bf16, once ---
#pragma unroll
    for (int it = 0; it < 16; ++it) {
        int idx = it * 256 + tid;       // float4 slot 0..4095
        int r   = idx >> 5;
        int c4  = idx & 31;
        float4 wv = *(const float4*)(W + (size_t)r * NF + c4 * 4);
        short4v wsv;
        wsv[0] = (short)f2bf(wv.x); wsv[1] = (short)f2bf(wv.y);
        wsv[2] = (short)f2bf(wv.z); wsv[3] = (short)f2bf(wv.w);
        *(short4v*)&wsh[r * LDW + c4 * 4] = wsv;
    }
    __syncthreads();

    const int w    = tid >> 6;
    const int lane = tid & 63;
    const int q    = lane >> 4;
    const int l15  = lane & 15;
    const int r0   = blockIdx.x * 128 + w * 32;

    const float* xp[2];
#pragma unroll
    for (int i = 0; i < 2; ++i) {
        int gr = r0 + i * 16 + l15;
        gr = gr < M ? gr : M - 1;       // clamp: OOB rows computed, never stored
        xp[i] = x + (size_t)gr * NF + q * 8;
    }

    ffrag acc[2][8];
#pragma unroll
    for (int i = 0; i < 2; ++i)
#pragma unroll
        for (int j = 0; j < 8; ++j) acc[i][j] = (ffrag)0.f;

#pragma unroll 2
    for (int kc = 0; kc < 4; ++kc) {    // K-chunks of 32; NO barriers inside
        bfrag a[2];
#pragma unroll
        for (int i = 0; i < 2; ++i) {
            float4 u0 = *(const float4*)(xp[i] + kc * 32);
            float4 u1 = *(const float4*)(xp[i] + kc * 32 + 4);
            bfrag tt;
            tt[0] = (short)f2bf(u0.x); tt[1] = (short)f2bf(u0.y);
            tt[2] = (short)f2bf(u0.z); tt[3] = (short)f2bf(u0.w);
            tt[4] = (short)f2bf(u1.x); tt[5] = (short)f2bf(u1.y);
            tt[6] = (short)f2bf(u1.z); tt[7] = (short)f2bf(u1.w);
            a[i] = tt;
        }
#pragma unroll
        for (int j = 0; j < 8; ++j) {
            bfrag b = *(const bfrag*)&wsh[(j * 16 + l15) * LDW + kc * 32 + q * 8];
            acc[0][j] = __builtin_amdgcn_mfma_f32_16x16x32_bf16(
                a[0], b, acc[0][j], 0, 0, 0);
            acc[1][j] = __builtin_amdgcn_mfma_f32_16x16x32_bf16(
                a[1], b, acc[1][j], 0, 0, 0);
        }
    }

    // --- epilogue: repack through LDS (reuses wsh), coalesced 16 B stores ---
    __syncthreads();
    short* tile = wsh;
#pragma unroll
    for (int i = 0; i < 2; ++i)
#pragma unroll
        for (int reg = 0; reg < 4; ++reg) {
            int row = w * 32 + i * 16 + q * 4 + reg;
#pragma unroll
            for (int j = 0; j < 8; ++j)
                tile[row * LDW + j * 16 + l15] = (short)f2bf(acc[i][j][reg]);
        }
    __syncthreads();
#pragma unroll
    for (int it = 0; it < 8; ++it) {
        int row = it * 16 + (tid >> 4);
        int m   = blockIdx.x * 128 + row;
        if (m < M) {
            int n  = m % NN;
            int bb = m / NN;
            uint4 v = *(const uint4*)&tile[row * LDW + (tid & 15) * 8];
            *(uint4*)(h + ((size_t)n * NB + bb) * NF + (tid & 15) * 8) = v;
        }
    }
}

// ---------------------------------------------------------------------------
// Merged scan (replaces scan1+scan2+scan3): ONE 1024-thread block walks the
// node space in 49 COALESCED chunks (thread t handles node ch*1024+t -- the
// R4 regression was per-thread STRIDED chunks, 64 lines/wave-load; this is
// lane-contiguous).  Per chunk: load the 8 per-copy counts (kept in regs),
// block-exclusive-scan the totals with a running carry, write rs, and write
// the per-copy segment-END cursors from the same registers.  cnt8 is read
// once (scan1+scan3 read it twice).  -2 launches.
// ---------------------------------------------------------------------------
__global__ __launch_bounds__(1024) void scan_kernel(
    int* __restrict__ cnt8, int* __restrict__ rs)
{
    __shared__ int wsum[16];
    const int tid  = threadIdx.x;
    const int lane = tid & 63;
    const int wid  = tid >> 6;

    int carry = 0;                       // replicated across all threads
    for (int ch = 0; ch < 49; ++ch) {
        const int i = ch * 1024 + tid;
        int vc[NCPY];
        int v = 0;
        if (i < NN) {
#pragma unroll
            for (int c = 0; c < NCPY; ++c) {
                vc[c] = cnt8[c * NNP + i];
                v += vc[c];
            }
        }
        int incl = v;
#pragma unroll
        for (int off = 1; off < 64; off <<= 1) {
            int t = __shfl_up(incl, off, 64);
            if (lane >= off) incl += t;
        }
        __syncthreads();                 // wsum from previous chunk consumed
        if (lane == 63) wsum[wid] = incl;
        __syncthreads();
        int woff = 0, chunktot = 0;
#pragma unroll
        for (int ww = 0; ww < 16; ++ww) {
            int s = wsum[ww];
            if (ww < wid) woff += s;
            chunktot += s;
        }
        if (i < NN) {
            int run = carry + woff + incl - v;   // global exclusive offset
            rs[i] = run;
#pragma unroll
            for (int c = 0; c < NCPY; ++c) {
                run += vc[c];
                cnt8[c * NNP + i] = run;          // copy-c segment end cursor
            }
        }
        carry += chunktot;
    }
    if (tid == 0) rs[NN] = NE;
}

// ---------------------------------------------------------------------------
// Scatter: dst straight from the privatized cursor (atomicSub counts the
// segment down).  UNCHANGED from R7.
// ---------------------------------------------------------------------------
__global__ void scatter_kernel(const int* __restrict__ row,
                               const int* __restrict__ col,
                               const float* __restrict__ val,
                               int* __restrict__ cur8,
                               uint2* __restrict__ cv_s)
{
    int e = blockIdx.x * 256 + threadIdx.x;
    if (e < NE) {
        int r = row[e];
        int p = atomicSub(&cur8[(e & 7) * NNP + r], 1) - 1;
        uint2 cv;
        cv.x = (unsigned)col[e];
        cv.y = __builtin_bit_cast(unsigned, val[e]);
        cv_s[p] = cv;                      // single 8 B write per edge
    }
}

// ---------------------------------------------------------------------------
// SpMM: wave per output row (body unchanged; proven floor ~126 us total).
// Split into two row-half dispatches (r0 = 0 / 25000) so each half (~63 us)
// drops below gemm/scatter in the top-5 and the front end finally gets
// counter rows.  The h-gather is a stationary random process, so per-half
// L2 behavior is unchanged and the split is ~free.
// ---------------------------------------------------------------------------
__global__ __launch_bounds__(256) void spmm_kernel(
    const unsigned short* __restrict__ h,   // [NN][NB][NF] bf16
    const int* __restrict__ rs,             // final CSR offsets (rs[NN]=NE)
    const uint2* __restrict__ cv_s,         // packed (col, val)
    float* __restrict__ out,                // [NB][NN][NF] fp32
    int r0)
{
    const int w    = threadIdx.x >> 6;
    const int lane = threadIdx.x & 63;
    int r = r0 + blockIdx.x * 4 + w;
    if (r >= NN) return;
    r = __builtin_amdgcn_readfirstlane(r);  // wave-uniform by construction

    const int s = rs[r];
    const int e = rs[r + 1];
    const int b    = lane >> 4;
    const int loff = b * NF + (lane & 15) * 8;   // element offset within h row

    float acc[8];
#pragma unroll
    for (int k = 0; k < 8; ++k) acc[k] = 0.f;

    for (int base = s; base < e; base += 64) {
        const int n = min(64, e - base);
        // coalesced preload of up to 64 edges; inactive lanes -> (col=0,val=0)
        unsigned long long cvp = 0ull;
        if (lane < n)
            cvp = __builtin_nontemporal_load(
                      (const unsigned long long*)(cv_s + base + lane));
        const int cvx = (int)(unsigned)(cvp & 0xffffffffull);   // col
        const int cvy = (int)(unsigned)(cvp >> 32);             // val bits

        const int n4 = (n + 3) & ~3;   // padded: lanes >= n contribute 0
        for (int i = 0; i < n4; i += 4) {
            const unsigned c0 = (unsigned)__builtin_amdgcn_readlane(cvx, i);
            const unsigned c1 = (unsigned)__builtin_amdgcn_readlane(cvx, i + 1);
            const unsigned c2 = (unsigned)__builtin_amdgcn_readlane(cvx, i + 2);
            const unsigned c3 = (unsigned)__builtin_amdgcn_readlane(cvx, i + 3);
            const uint4 q0 = *(const uint4*)(h + (size_t)c0 * (NB * NF) + loff);
            const uint4 q1 = *(const uint4*)(h + (size_t)c1 * (NB * NF) + loff);
            const uint4 q2 = *(const uint4*)(h + (size_t)c2 * (NB * NF) + loff);
            const uint4 q3 = *(const uint4*)(h + (size_t)c3 * (NB * NF) + loff);
            const float v0 = __builtin_bit_cast(
                float, __builtin_amdgcn_readlane(cvy, i));
            const float v1 = __builtin_bit_cast(
                float, __builtin_amdgcn_readlane(cvy, i + 1));
            const float v2 = __builtin_bit_cast(
                float, __builtin_amdgcn_readlane(cvy, i + 2));
            const float v3 = __builtin_bit_cast(
                float, __builtin_amdgcn_readlane(cvy, i + 3));

            acc[0] += v0 * bflo(q0.x); acc[1] += v0 * bfhi(q0.x);
            acc[2] += v0 * bflo(q0.y); acc[3] += v0 * bfhi(q0.y);
            acc[4] += v0 * bflo(q0.z); acc[5] += v0 * bfhi(q0.z);
            acc[6] += v0 * bflo(q0.w); acc[7] += v0 * bfhi(q0.w);
            acc[0] += v1 * bflo(q1.x); acc[1] += v1 * bfhi(q1.x);
            acc[2] += v1 * bflo(q1.y); acc[3] += v1 * bfhi(q1.y);
            acc[4] += v1 * bflo(q1.z); acc[5] += v1 * bfhi(q1.z);
            acc[6] += v1 * bflo(q1.w); acc[7] += v1 * bfhi(q1.w);
            acc[0] += v2 * bflo(q2.x); acc[1] += v2 * bfhi(q2.x);
            acc[2] += v2 * bflo(q2.y); acc[3] += v2 * bfhi(q2.y);
            acc[4] += v2 * bflo(q2.z); acc[5] += v2 * bfhi(q2.z);
            acc[6] += v2 * bflo(q2.w); acc[7] += v2 * bfhi(q2.w);
            acc[0] += v3 * bflo(q3.x); acc[1] += v3 * bfhi(q3.x);
            acc[2] += v3 * bflo(q3.y); acc[3] += v3 * bfhi(q3.y);
            acc[4] += v3 * bflo(q3.z); acc[5] += v3 * bfhi(q3.z);
            acc[6] += v3 * bflo(q3.w); acc[7] += v3 * bfhi(q3.w);
        }
    }

    float* op = out + ((size_t)b * NN + r) * NF + (lane & 15) * 8;
    *(float4*)op       = make_float4(acc[0], acc[1], acc[2], acc[3]);
    *(float4*)(op + 4) = make_float4(acc[4], acc[5], acc[6], acc[7]);
}

// ---------------------------------------------------------------------------
extern "C" void kernel_launch(void* const* d_in, const int* in_sizes, int n_in,
                              void* d_out, int out_size, void* d_ws, size_t ws_size,
                              hipStream_t stream)
{
    const float* x    = (const float*)d_in[0];
    const float* W    = (const float*)d_in[1];
    const int*   erow = (const int*)d_in[2];
    const int*   ecol = (const int*)d_in[3];
    const float* ev   = (const float*)d_in[4];
    float*       out  = (float*)d_out;

    char*  ws  = (char*)d_ws;
    size_t off = 0;
    auto alloc = [&](size_t bytes) -> void* {
        void* p = ws + off;
        off += (bytes + 255) & ~(size_t)255;
        return p;
    };
    unsigned short* h = (unsigned short*)alloc((size_t)NN * NB * NF * sizeof(unsigned short)); // 51.2 MB
    int*   rs   = (int*)  alloc((size_t)(NN + 1) * sizeof(int));
    int*   cnt8 = (int*)  alloc((size_t)NCPY * NNP * sizeof(int));   // 1.6 MB
    uint2* cv_s = (uint2*)alloc((size_t)NE * sizeof(uint2));

    hipMemsetAsync(cnt8, 0, (size_t)NCPY * NNP * sizeof(int), stream);

    const int M = NB * NN;
    gemm_kernel<<<NTILE, 256, 0, stream>>>(x, W, h, erow, cnt8, M);

    scan_kernel<<<1, 1024, 0, stream>>>(cnt8, rs);
    scatter_kernel<<<(NE + 255) / 256, 256, 0, stream>>>(erow, ecol, ev,
                                                         cnt8, cv_s);

    spmm_kernel<<<6250, 256, 0, stream>>>(h, rs, cv_s, out, 0);
    spmm_kernel<<<6250, 256, 0, stream>>>(h, rs, cv_s, out, 25000);
}